// Round 1
// baseline (354.619 us; speedup 1.0000x reference)
//
#include <hip/hip_runtime.h>
#include <hip/hip_bf16.h>

typedef unsigned short u16;
typedef __attribute__((ext_vector_type(8))) short short8;
typedef __attribute__((ext_vector_type(4))) float f32x4;

#define N_TOKENS 4096
#define HIDDEN   1024
#define N_EXP    8
#define EXPAND   2048

// ---------- workspace layout (bytes) ----------
#define TOKB_OFF 0ull                    // bf16 tokens      [4096][1024]   8,388,608
#define W1T_OFF  8388608ull              // bf16 w1^T        [8][2048][1024] 33,554,432
#define W2T_OFF  41943040ull             // bf16 w2^T        [8][1024][2048] 33,554,432
#define H_OFF    75497472ull             // bf16 h           [8192][2048]   33,554,432
#define RLT_OFF  109051904ull            // int rowlist_token[8192]
#define RLG_OFF  109084672ull            // float rowlist_gate[8192]
#define CNT_OFF  109117440ull            // int cnt[8]
#define BASE_OFF 109117472ull            // int base[8]
#define E01_OFF  109117504ull            // int e01[4096][2]
#define SLOT_OFF 109150272ull            // int slots[4096][2]
#define GATE_OFF 109183040ull            // float gates[4096][2]

__device__ __forceinline__ u16 f2bf(float f) {
  union { float f; unsigned u; } v; v.f = f;
  unsigned r = v.u + 0x7fffu + ((v.u >> 16) & 1u);   // round-to-nearest-even
  return (u16)(r >> 16);
}

__device__ __forceinline__ void glds16(const void* g, void* l) {
  __builtin_amdgcn_global_load_lds(
      (const __attribute__((address_space(1))) void*)g,
      (__attribute__((address_space(3))) void*)l, 16, 0, 0);
}

// ---------- tokens fp32 -> bf16 ----------
__global__ __launch_bounds__(256) void cvt_tokens_k(const float* __restrict__ in,
                                                    u16* __restrict__ out) {
  int i = blockIdx.x * 256 + threadIdx.x;      // index in float4 units
  const float4 v = ((const float4*)in)[i];
  ushort4 o;
  o.x = f2bf(v.x); o.y = f2bf(v.y); o.z = f2bf(v.z); o.w = f2bf(v.w);
  ((ushort4*)out)[i] = o;
}

// ---------- fp32 [E][R][C] -> bf16 [E][C][R] ----------
__global__ __launch_bounds__(256) void cvt_transpose_k(const float* __restrict__ in,
                                                       u16* __restrict__ out,
                                                       int R, int C) {
  __shared__ float t[32][33];
  int e = blockIdx.z;
  int r0 = blockIdx.y * 32, c0 = blockIdx.x * 32;
  const float* ip = in + (size_t)e * R * C;
  u16* op = out + (size_t)e * R * C;
  int tx = threadIdx.x, ty = threadIdx.y;
  #pragma unroll
  for (int i = 0; i < 4; ++i)
    t[ty + i * 8][tx] = ip[(size_t)(r0 + ty + i * 8) * C + c0 + tx];
  __syncthreads();
  #pragma unroll
  for (int i = 0; i < 4; ++i)
    op[(size_t)(c0 + ty + i * 8) * R + r0 + tx] = f2bf(t[tx][ty + i * 8]);
}

// ---------- router: fp32 logits, top-2, softmax, bucket counts ----------
__global__ __launch_bounds__(256) void router_k(const float* __restrict__ tokens,
                                                const float* __restrict__ rw,
                                                const float* __restrict__ rb,
                                                int* __restrict__ e01,
                                                int* __restrict__ slots,
                                                float* __restrict__ gates,
                                                int* __restrict__ cnt) {
  __shared__ float rwl[N_EXP * HIDDEN];
  int tid = threadIdx.x;
  for (int i = tid; i < N_EXP * HIDDEN; i += 256) rwl[i] = rw[i];
  __syncthreads();
  int w = tid >> 6, l = tid & 63;
  int t = blockIdx.x * 4 + w;
  const float* tp = tokens + (size_t)t * HIDDEN;
  float acc[8] = {0.f,0.f,0.f,0.f,0.f,0.f,0.f,0.f};
  for (int k = l; k < HIDDEN; k += 64) {
    float tv = tp[k];
    #pragma unroll
    for (int e = 0; e < 8; ++e) acc[e] += tv * rwl[e * HIDDEN + k];
  }
  #pragma unroll
  for (int off = 32; off >= 1; off >>= 1) {
    #pragma unroll
    for (int e = 0; e < 8; ++e) acc[e] += __shfl_xor(acc[e], off);
  }
  if (l == 0) {
    float lg[8];
    #pragma unroll
    for (int e = 0; e < 8; ++e) lg[e] = acc[e] + rb[e];
    int b0 = 0; float v0 = lg[0];
    #pragma unroll
    for (int e = 1; e < 8; ++e) if (lg[e] > v0) { v0 = lg[e]; b0 = e; }
    int b1 = -1; float v1 = -3.4e38f;
    #pragma unroll
    for (int e = 0; e < 8; ++e) {
      if (e == b0) continue;
      if (lg[e] > v1) { v1 = lg[e]; b1 = e; }
    }
    float d = expf(v1 - v0);
    float p1 = d / (1.f + d);
    float p0 = 1.f - p1;
    int s0 = atomicAdd(&cnt[b0], 1);
    int s1 = atomicAdd(&cnt[b1], 1);
    e01[t * 2] = b0;   e01[t * 2 + 1] = b1;
    slots[t * 2] = s0; slots[t * 2 + 1] = s1;
    gates[t * 2] = p0; gates[t * 2 + 1] = p1;
  }
}

__global__ void scan_k(const int* __restrict__ cnt, int* __restrict__ base) {
  if (threadIdx.x == 0) {
    int s = 0;
    for (int e = 0; e < N_EXP; ++e) { base[e] = s; s += cnt[e]; }
  }
}

__global__ __launch_bounds__(256) void build_k(const int* __restrict__ e01,
                                               const int* __restrict__ slots,
                                               const float* __restrict__ gates,
                                               const int* __restrict__ base,
                                               int* __restrict__ rlt,
                                               float* __restrict__ rlg) {
  int t = blockIdx.x * 256 + threadIdx.x;
  if (t >= N_TOKENS) return;
  #pragma unroll
  for (int k = 0; k < 2; ++k) {
    int e = e01[t * 2 + k];
    int row = base[e] + slots[t * 2 + k];
    rlt[row] = t;
    rlg[row] = gates[t * 2 + k];
  }
}

// ---------- stage 1: h = gelu(tok_rows @ w1[e] + b1[e]) ----------
// grid (16, 32, 8) = (n-tile of 2048, m-tile of 4096cap, expert); 256 thr, 4 waves.
// Tile 128x128, BK=64. A gathered by token id. XOR chunk swizzle (slot = chunk ^ (row&7)).
__global__ __launch_bounds__(256) void ffn1_k(const u16* __restrict__ tok,
                                              const u16* __restrict__ w1t,
                                              const float* __restrict__ b1,
                                              const int* __restrict__ rlt,
                                              const int* __restrict__ cnt,
                                              const int* __restrict__ base,
                                              u16* __restrict__ h) {
  int e = blockIdx.z, mt = blockIdx.y, nt = blockIdx.x;
  int ne = cnt[e];
  if (mt * 128 >= ne) return;
  int m0g = base[e] + mt * 128;

  __shared__ __align__(16) short A[128 * 64];
  __shared__ __align__(16) short B[128 * 64];
  __shared__ int rtok[128];

  int tid = threadIdx.x;
  if (tid < 128) {
    int lr = mt * 128 + tid;
    rtok[tid] = (lr < ne) ? rlt[m0g + tid] : 0;
  }
  __syncthreads();

  int w = tid >> 6, l = tid & 63;
  int wr = w >> 1, wc = w & 1;
  int dchunk = (l & 7) ^ (l >> 3);          // pre-swizzled global source chunk

  const u16* ga[4]; const u16* gb[4];
  #pragma unroll
  for (int c = 0; c < 4; ++c) {
    int q = w + 4 * c;                       // 0..15 chunk of 8 rows
    int row = q * 8 + (l >> 3);              // 0..127
    ga[c] = tok + (size_t)rtok[row] * HIDDEN + dchunk * 8;
    int nrow = nt * 128 + row;
    gb[c] = w1t + (size_t)e * EXPAND * HIDDEN + (size_t)nrow * HIDDEN + dchunk * 8;
  }

  f32x4 acc[4][4] = {};
  for (int kt = 0; kt < HIDDEN / 64; ++kt) {
    __syncthreads();
    #pragma unroll
    for (int c = 0; c < 4; ++c) {
      glds16(ga[c] + kt * 64, &A[(w + 4 * c) * 512]);
      glds16(gb[c] + kt * 64, &B[(w + 4 * c) * 512]);
    }
    __syncthreads();
    short8 af[4][2], bf[4][2];
    #pragma unroll
    for (int i = 0; i < 4; ++i) {
      int ra = wr * 64 + i * 16 + (l & 15);
      int rb_ = wc * 64 + i * 16 + (l & 15);
      #pragma unroll
      for (int kk = 0; kk < 2; ++kk) {
        int cc = kk * 4 + (l >> 4);
        af[i][kk] = *(const short8*)&A[ra * 64 + (cc ^ (ra & 7)) * 8];
        bf[i][kk] = *(const short8*)&B[rb_ * 64 + (cc ^ (rb_ & 7)) * 8];
      }
    }
    #pragma unroll
    for (int i = 0; i < 4; ++i) {
      #pragma unroll
      for (int j = 0; j < 4; ++j) {
        acc[i][j] = __builtin_amdgcn_mfma_f32_16x16x32_bf16(af[i][0], bf[j][0], acc[i][j], 0, 0, 0);
        acc[i][j] = __builtin_amdgcn_mfma_f32_16x16x32_bf16(af[i][1], bf[j][1], acc[i][j], 0, 0, 0);
      }
    }
  }

  int mrem = ne - mt * 128;
  #pragma unroll
  for (int i = 0; i < 4; ++i) {
    #pragma unroll
    for (int r = 0; r < 4; ++r) {
      int row = wr * 64 + i * 16 + (l >> 4) * 4 + r;
      if (row >= mrem) continue;
      size_t hrow = (size_t)(m0g + row) * EXPAND;
      #pragma unroll
      for (int j = 0; j < 4; ++j) {
        int col = nt * 128 + wc * 64 + j * 16 + (l & 15);
        float x = acc[i][j][r] + b1[e * EXPAND + col];
        float g = 0.5f * x * (1.0f + erff(x * 0.70710678118654752f));
        h[hrow + col] = f2bf(g);
      }
    }
  }
}

// ---------- stage 2: out[tok] += gate * (h_rows @ w2[e] + b2[e]) ----------
// grid (8, 32, 8); same tile structure, contiguous A rows, atomic scatter epilogue.
__global__ __launch_bounds__(256) void ffn2_k(const u16* __restrict__ h,
                                              const u16* __restrict__ w2t,
                                              const float* __restrict__ b2,
                                              const int* __restrict__ rlt,
                                              const float* __restrict__ rlg,
                                              const int* __restrict__ cnt,
                                              const int* __restrict__ base,
                                              float* __restrict__ out) {
  int e = blockIdx.z, mt = blockIdx.y, nt = blockIdx.x;
  int ne = cnt[e];
  if (mt * 128 >= ne) return;
  int m0g = base[e] + mt * 128;

  __shared__ __align__(16) short A[128 * 64];
  __shared__ __align__(16) short B[128 * 64];
  __shared__ int rtok[128];
  __shared__ float rgat[128];

  int tid = threadIdx.x;
  if (tid < 128) {
    int lr = mt * 128 + tid;
    int ok = lr < ne;
    rtok[tid] = ok ? rlt[m0g + tid] : 0;
    rgat[tid] = ok ? rlg[m0g + tid] : 0.f;
  }
  __syncthreads();

  int w = tid >> 6, l = tid & 63;
  int wr = w >> 1, wc = w & 1;
  int dchunk = (l & 7) ^ (l >> 3);

  const u16* ga[4]; const u16* gb[4];
  #pragma unroll
  for (int c = 0; c < 4; ++c) {
    int q = w + 4 * c;
    int row = q * 8 + (l >> 3);
    int rowg = m0g + row; if (rowg > 8191) rowg = 8191;    // clamped tail reads
    ga[c] = h + (size_t)rowg * EXPAND + dchunk * 8;
    int nrow = nt * 128 + row;
    gb[c] = w2t + (size_t)e * HIDDEN * EXPAND + (size_t)nrow * EXPAND + dchunk * 8;
  }

  f32x4 acc[4][4] = {};
  for (int kt = 0; kt < EXPAND / 64; ++kt) {
    __syncthreads();
    #pragma unroll
    for (int c = 0; c < 4; ++c) {
      glds16(ga[c] + kt * 64, &A[(w + 4 * c) * 512]);
      glds16(gb[c] + kt * 64, &B[(w + 4 * c) * 512]);
    }
    __syncthreads();
    short8 af[4][2], bf[4][2];
    #pragma unroll
    for (int i = 0; i < 4; ++i) {
      int ra = wr * 64 + i * 16 + (l & 15);
      int rb_ = wc * 64 + i * 16 + (l & 15);
      #pragma unroll
      for (int kk = 0; kk < 2; ++kk) {
        int cc = kk * 4 + (l >> 4);
        af[i][kk] = *(const short8*)&A[ra * 64 + (cc ^ (ra & 7)) * 8];
        bf[i][kk] = *(const short8*)&B[rb_ * 64 + (cc ^ (rb_ & 7)) * 8];
      }
    }
    #pragma unroll
    for (int i = 0; i < 4; ++i) {
      #pragma unroll
      for (int j = 0; j < 4; ++j) {
        acc[i][j] = __builtin_amdgcn_mfma_f32_16x16x32_bf16(af[i][0], bf[j][0], acc[i][j], 0, 0, 0);
        acc[i][j] = __builtin_amdgcn_mfma_f32_16x16x32_bf16(af[i][1], bf[j][1], acc[i][j], 0, 0, 0);
      }
    }
  }

  int mrem = ne - mt * 128;
  #pragma unroll
  for (int i = 0; i < 4; ++i) {
    #pragma unroll
    for (int r = 0; r < 4; ++r) {
      int row = wr * 64 + i * 16 + (l >> 4) * 4 + r;
      if (row >= mrem) continue;
      int token = rtok[row];
      float gate = rgat[row];
      #pragma unroll
      for (int j = 0; j < 4; ++j) {
        int col = nt * 128 + wc * 64 + j * 16 + (l & 15);
        float val = (acc[i][j][r] + b2[e * HIDDEN + col]) * gate;
        atomicAdd(&out[(size_t)token * HIDDEN + col], val);
      }
    }
  }
}

extern "C" void kernel_launch(void* const* d_in, const int* in_sizes, int n_in,
                              void* d_out, int out_size, void* d_ws, size_t ws_size,
                              hipStream_t stream) {
  const float* tokens   = (const float*)d_in[0];
  const float* router_w = (const float*)d_in[1];
  const float* router_b = (const float*)d_in[2];
  const float* w1       = (const float*)d_in[3];
  const float* b1       = (const float*)d_in[4];
  const float* w2       = (const float*)d_in[5];
  const float* b2       = (const float*)d_in[6];
  float* out = (float*)d_out;

  char* ws = (char*)d_ws;
  u16*   tokb  = (u16*)(ws + TOKB_OFF);
  u16*   w1t   = (u16*)(ws + W1T_OFF);
  u16*   w2t   = (u16*)(ws + W2T_OFF);
  u16*   h     = (u16*)(ws + H_OFF);
  int*   rlt   = (int*)(ws + RLT_OFF);
  float* rlg   = (float*)(ws + RLG_OFF);
  int*   cnt   = (int*)(ws + CNT_OFF);
  int*   basep = (int*)(ws + BASE_OFF);
  int*   e01   = (int*)(ws + E01_OFF);
  int*   slots = (int*)(ws + SLOT_OFF);
  float* gates = (float*)(ws + GATE_OFF);

  hipMemsetAsync(cnt, 0, 64, stream);                          // cnt + base
  hipMemsetAsync(d_out, 0, (size_t)out_size * sizeof(float), stream);

  cvt_tokens_k<<<(N_TOKENS * HIDDEN / 4) / 256, 256, 0, stream>>>(tokens, tokb);
  cvt_transpose_k<<<dim3(EXPAND / 32, HIDDEN / 32, N_EXP), dim3(32, 8), 0, stream>>>(
      w1, w1t, HIDDEN, EXPAND);
  cvt_transpose_k<<<dim3(HIDDEN / 32, EXPAND / 32, N_EXP), dim3(32, 8), 0, stream>>>(
      w2, w2t, EXPAND, HIDDEN);
  router_k<<<N_TOKENS / 4, 256, 0, stream>>>(tokens, router_w, router_b,
                                             e01, slots, gates, cnt);
  scan_k<<<1, 64, 0, stream>>>(cnt, basep);
  build_k<<<N_TOKENS / 256, 256, 0, stream>>>(e01, slots, gates, basep, rlt, rlg);
  ffn1_k<<<dim3(EXPAND / 128, 32, N_EXP), 256, 0, stream>>>(tokb, w1t, b1, rlt, cnt, basep, h);
  ffn2_k<<<dim3(HIDDEN / 128, 32, N_EXP), 256, 0, stream>>>(h, w2t, b2, rlt, rlg, cnt, basep, out);
}

// Round 2
// 339.259 us; speedup vs baseline: 1.0453x; 1.0453x over previous
//
#include <hip/hip_runtime.h>
#include <hip/hip_bf16.h>

typedef unsigned short u16;
typedef __attribute__((ext_vector_type(8))) short short8;
typedef __attribute__((ext_vector_type(4))) float f32x4;

#define N_TOKENS 4096
#define HIDDEN   1024
#define N_EXP    8
#define EXPAND   2048

// ---------- workspace layout (bytes) ----------
#define TOKB_OFF  0ull                   // bf16 tokens      [4096][1024]    8,388,608
#define W1T_OFF   8388608ull             // bf16 w1^T        [8][2048][1024] 33,554,432
#define OBUF_OFF  8388608ull             // fp32 obuf        [8192][1024]    33,554,432 (reuses w1t after ffn1)
#define W2T_OFF   41943040ull            // bf16 w2^T        [8][1024][2048] 33,554,432
#define H_OFF     75497472ull            // bf16 h           [8192][2048]    33,554,432
#define RLT_OFF   109051904ull           // int rowlist_token[8192]
#define RLG_OFF   109084672ull           // float rowlist_gate[8192]
#define CNT_OFF   109117440ull           // int cnt[8]
#define E01_OFF   109117472ull           // int e01[4096][2]
#define SLOT_OFF  109150240ull           // int slots[4096][2]
#define GATE_OFF  109183008ull           // float gates[4096][2]
#define ROWS2_OFF 109215776ull           // int rows2[4096][2]  (token -> its 2 rows)

__device__ __forceinline__ u16 f2bf(float f) {
  union { float f; unsigned u; } v; v.f = f;
  unsigned r = v.u + 0x7fffu + ((v.u >> 16) & 1u);   // round-to-nearest-even
  return (u16)(r >> 16);
}

__device__ __forceinline__ void glds16(const void* g, void* l) {
  __builtin_amdgcn_global_load_lds(
      (const __attribute__((address_space(1))) void*)g,
      (__attribute__((address_space(3))) void*)l, 16, 0, 0);
}

// expert -> (base, count) from cnt[8], computed redundantly per block (L2-hot)
__device__ __forceinline__ void expert_range(const int* __restrict__ cnt, int e,
                                             int& m0, int& ne) {
  m0 = 0; ne = 0;
  #pragma unroll
  for (int i = 0; i < N_EXP; ++i) {
    int ci = cnt[i];
    if (i < e) m0 += ci;
    if (i == e) ne = ci;
  }
}

// ---------- tokens fp32 -> bf16 ----------
__global__ __launch_bounds__(256) void cvt_tokens_k(const float* __restrict__ in,
                                                    u16* __restrict__ out) {
  int i = blockIdx.x * 256 + threadIdx.x;      // index in float4 units
  const float4 v = ((const float4*)in)[i];
  ushort4 o;
  o.x = f2bf(v.x); o.y = f2bf(v.y); o.z = f2bf(v.z); o.w = f2bf(v.w);
  ((ushort4*)out)[i] = o;
}

// ---------- fp32 [E][R][C] -> bf16 [E][C][R] ----------
__global__ __launch_bounds__(256) void cvt_transpose_k(const float* __restrict__ in,
                                                       u16* __restrict__ out,
                                                       int R, int C) {
  __shared__ float t[32][33];
  int e = blockIdx.z;
  int r0 = blockIdx.y * 32, c0 = blockIdx.x * 32;
  const float* ip = in + (size_t)e * R * C;
  u16* op = out + (size_t)e * R * C;
  int tx = threadIdx.x, ty = threadIdx.y;
  #pragma unroll
  for (int i = 0; i < 4; ++i)
    t[ty + i * 8][tx] = ip[(size_t)(r0 + ty + i * 8) * C + c0 + tx];
  __syncthreads();
  #pragma unroll
  for (int i = 0; i < 4; ++i)
    op[(size_t)(c0 + ty + i * 8) * R + r0 + tx] = f2bf(t[tx][ty + i * 8]);
}

// ---------- router: fp32 logits, top-2, softmax, bucket counts ----------
__global__ __launch_bounds__(256) void router_k(const float* __restrict__ tokens,
                                                const float* __restrict__ rw,
                                                const float* __restrict__ rb,
                                                int* __restrict__ e01,
                                                int* __restrict__ slots,
                                                float* __restrict__ gates,
                                                int* __restrict__ cnt) {
  __shared__ float rwl[N_EXP * HIDDEN];
  int tid = threadIdx.x;
  for (int i = tid; i < N_EXP * HIDDEN; i += 256) rwl[i] = rw[i];
  __syncthreads();
  int w = tid >> 6, l = tid & 63;
  int t = blockIdx.x * 4 + w;
  const float* tp = tokens + (size_t)t * HIDDEN;
  float acc[8] = {0.f,0.f,0.f,0.f,0.f,0.f,0.f,0.f};
  for (int k = l; k < HIDDEN; k += 64) {
    float tv = tp[k];
    #pragma unroll
    for (int e = 0; e < 8; ++e) acc[e] += tv * rwl[e * HIDDEN + k];
  }
  #pragma unroll
  for (int off = 32; off >= 1; off >>= 1) {
    #pragma unroll
    for (int e = 0; e < 8; ++e) acc[e] += __shfl_xor(acc[e], off);
  }
  if (l == 0) {
    float lg[8];
    #pragma unroll
    for (int e = 0; e < 8; ++e) lg[e] = acc[e] + rb[e];
    int b0 = 0; float v0 = lg[0];
    #pragma unroll
    for (int e = 1; e < 8; ++e) if (lg[e] > v0) { v0 = lg[e]; b0 = e; }
    int b1 = -1; float v1 = -3.4e38f;
    #pragma unroll
    for (int e = 0; e < 8; ++e) {
      if (e == b0) continue;
      if (lg[e] > v1) { v1 = lg[e]; b1 = e; }
    }
    float d = expf(v1 - v0);
    float p1 = d / (1.f + d);
    float p0 = 1.f - p1;
    int s0 = atomicAdd(&cnt[b0], 1);
    int s1 = atomicAdd(&cnt[b1], 1);
    e01[t * 2] = b0;   e01[t * 2 + 1] = b1;
    slots[t * 2] = s0; slots[t * 2 + 1] = s1;
    gates[t * 2] = p0; gates[t * 2 + 1] = p1;
  }
}

__global__ __launch_bounds__(256) void build_k(const int* __restrict__ e01,
                                               const int* __restrict__ slots,
                                               const float* __restrict__ gates,
                                               const int* __restrict__ cnt,
                                               int* __restrict__ rlt,
                                               float* __restrict__ rlg,
                                               int* __restrict__ rows2) {
  int t = blockIdx.x * 256 + threadIdx.x;
  if (t >= N_TOKENS) return;
  #pragma unroll
  for (int k = 0; k < 2; ++k) {
    int e = e01[t * 2 + k];
    int m0, ne;
    expert_range(cnt, e, m0, ne);
    int row = m0 + slots[t * 2 + k];
    rlt[row] = t;
    rlg[row] = gates[t * 2 + k];
    rows2[t * 2 + k] = row;
  }
}

// ---------- stage 1: h = gelu(tok_rows @ w1[e] + b1[e]) ----------
// 128x128 tile, BK=64, 4 waves, double-buffered LDS (64 KB), 2-phase pipeline:
// issue stage(t+1) before MFMA(t), single barrier per K-step.
__global__ __launch_bounds__(256) void ffn1_k(const u16* __restrict__ tok,
                                              const u16* __restrict__ w1t,
                                              const float* __restrict__ b1,
                                              const int* __restrict__ rlt,
                                              const int* __restrict__ cnt,
                                              u16* __restrict__ h) {
  int e = blockIdx.z, mt = blockIdx.y, nt = blockIdx.x;
  int m0, ne;
  expert_range(cnt, e, m0, ne);
  if (mt * 128 >= ne) return;
  int m0g = m0 + mt * 128;
  int mrem = ne - mt * 128;

  __shared__ __align__(16) short A[2][8192];
  __shared__ __align__(16) short B[2][8192];

  int tid = threadIdx.x, w = tid >> 6, l = tid & 63;
  int wr = w >> 1, wc = w & 1;
  int dchunk = (l & 7) ^ (l >> 3);          // pre-swizzled global source chunk

  const u16* ga[4]; const u16* gb[4];
  #pragma unroll
  for (int c = 0; c < 4; ++c) {
    int q = w + 4 * c;                       // chunk of 8 rows
    int row = q * 8 + (l >> 3);              // 0..127
    int tokid = (row < mrem) ? rlt[m0g + row] : 0;
    ga[c] = tok + (size_t)tokid * HIDDEN + dchunk * 8;
    int nrow = nt * 128 + row;
    gb[c] = w1t + (size_t)e * EXPAND * HIDDEN + (size_t)nrow * HIDDEN + dchunk * 8;
  }

  const int NK = HIDDEN / 64;
  #pragma unroll
  for (int c = 0; c < 4; ++c) {              // stage kt=0 -> buf 0
    glds16(ga[c], &A[0][(w + 4 * c) * 512]);
    glds16(gb[c], &B[0][(w + 4 * c) * 512]);
  }
  __syncthreads();

  f32x4 acc[4][4] = {};
  int cur = 0;
  for (int kt = 0; kt < NK; ++kt) {
    if (kt + 1 < NK) {
      #pragma unroll
      for (int c = 0; c < 4; ++c) {
        glds16(ga[c] + (kt + 1) * 64, &A[cur ^ 1][(w + 4 * c) * 512]);
        glds16(gb[c] + (kt + 1) * 64, &B[cur ^ 1][(w + 4 * c) * 512]);
      }
    }
    short8 af[4][2], bf[4][2];
    #pragma unroll
    for (int i = 0; i < 4; ++i) {
      int ra = wr * 64 + i * 16 + (l & 15);
      int rb_ = wc * 64 + i * 16 + (l & 15);
      #pragma unroll
      for (int kk = 0; kk < 2; ++kk) {
        int cc = kk * 4 + (l >> 4);
        af[i][kk] = *(const short8*)&A[cur][ra * 64 + (cc ^ (ra & 7)) * 8];
        bf[i][kk] = *(const short8*)&B[cur][rb_ * 64 + (cc ^ (rb_ & 7)) * 8];
      }
    }
    #pragma unroll
    for (int i = 0; i < 4; ++i) {
      #pragma unroll
      for (int j = 0; j < 4; ++j) {
        acc[i][j] = __builtin_amdgcn_mfma_f32_16x16x32_bf16(af[i][0], bf[j][0], acc[i][j], 0, 0, 0);
        acc[i][j] = __builtin_amdgcn_mfma_f32_16x16x32_bf16(af[i][1], bf[j][1], acc[i][j], 0, 0, 0);
      }
    }
    __syncthreads();                          // drains vmcnt -> next buf ready
    cur ^= 1;
  }

  #pragma unroll
  for (int i = 0; i < 4; ++i) {
    #pragma unroll
    for (int r = 0; r < 4; ++r) {
      int row = wr * 64 + i * 16 + (l >> 4) * 4 + r;
      if (row >= mrem) continue;
      size_t hrow = (size_t)(m0g + row) * EXPAND;
      #pragma unroll
      for (int j = 0; j < 4; ++j) {
        int col = nt * 128 + wc * 64 + j * 16 + (l & 15);
        float x = acc[i][j][r] + b1[e * EXPAND + col];
        float g = 0.5f * x * (1.0f + erff(x * 0.70710678118654752f));
        h[hrow + col] = f2bf(g);
      }
    }
  }
}

// ---------- stage 2: obuf[row] = gate * (h[row] @ w2[e] + b2[e]) ----------
__global__ __launch_bounds__(256) void ffn2_k(const u16* __restrict__ h,
                                              const u16* __restrict__ w2t,
                                              const float* __restrict__ b2,
                                              const float* __restrict__ rlg,
                                              const int* __restrict__ cnt,
                                              float* __restrict__ obuf) {
  int e = blockIdx.z, mt = blockIdx.y, nt = blockIdx.x;
  int m0, ne;
  expert_range(cnt, e, m0, ne);
  if (mt * 128 >= ne) return;
  int m0g = m0 + mt * 128;
  int mrem = ne - mt * 128;

  __shared__ __align__(16) short A[2][8192];
  __shared__ __align__(16) short B[2][8192];

  int tid = threadIdx.x, w = tid >> 6, l = tid & 63;
  int wr = w >> 1, wc = w & 1;
  int dchunk = (l & 7) ^ (l >> 3);

  const u16* ga[4]; const u16* gb[4];
  #pragma unroll
  for (int c = 0; c < 4; ++c) {
    int q = w + 4 * c;
    int row = q * 8 + (l >> 3);
    int rowg = m0g + row; if (rowg > 8191) rowg = 8191;   // clamped tail reads
    ga[c] = h + (size_t)rowg * EXPAND + dchunk * 8;
    int nrow = nt * 128 + row;
    gb[c] = w2t + (size_t)e * HIDDEN * EXPAND + (size_t)nrow * EXPAND + dchunk * 8;
  }

  const int NK = EXPAND / 64;
  #pragma unroll
  for (int c = 0; c < 4; ++c) {
    glds16(ga[c], &A[0][(w + 4 * c) * 512]);
    glds16(gb[c], &B[0][(w + 4 * c) * 512]);
  }
  __syncthreads();

  f32x4 acc[4][4] = {};
  int cur = 0;
  for (int kt = 0; kt < NK; ++kt) {
    if (kt + 1 < NK) {
      #pragma unroll
      for (int c = 0; c < 4; ++c) {
        glds16(ga[c] + (kt + 1) * 64, &A[cur ^ 1][(w + 4 * c) * 512]);
        glds16(gb[c] + (kt + 1) * 64, &B[cur ^ 1][(w + 4 * c) * 512]);
      }
    }
    short8 af[4][2], bf[4][2];
    #pragma unroll
    for (int i = 0; i < 4; ++i) {
      int ra = wr * 64 + i * 16 + (l & 15);
      int rb_ = wc * 64 + i * 16 + (l & 15);
      #pragma unroll
      for (int kk = 0; kk < 2; ++kk) {
        int cc = kk * 4 + (l >> 4);
        af[i][kk] = *(const short8*)&A[cur][ra * 64 + (cc ^ (ra & 7)) * 8];
        bf[i][kk] = *(const short8*)&B[cur][rb_ * 64 + (cc ^ (rb_ & 7)) * 8];
      }
    }
    #pragma unroll
    for (int i = 0; i < 4; ++i) {
      #pragma unroll
      for (int j = 0; j < 4; ++j) {
        acc[i][j] = __builtin_amdgcn_mfma_f32_16x16x32_bf16(af[i][0], bf[j][0], acc[i][j], 0, 0, 0);
        acc[i][j] = __builtin_amdgcn_mfma_f32_16x16x32_bf16(af[i][1], bf[j][1], acc[i][j], 0, 0, 0);
      }
    }
    __syncthreads();
    cur ^= 1;
  }

  #pragma unroll
  for (int i = 0; i < 4; ++i) {
    #pragma unroll
    for (int r = 0; r < 4; ++r) {
      int row = wr * 64 + i * 16 + (l >> 4) * 4 + r;
      if (row >= mrem) continue;
      float gate = rlg[m0g + row];
      size_t orow = (size_t)(m0g + row) * HIDDEN;
      #pragma unroll
      for (int j = 0; j < 4; ++j) {
        int col = nt * 128 + wc * 64 + j * 16 + (l & 15);
        obuf[orow + col] = (acc[i][j][r] + b2[e * HIDDEN + col]) * gate;
      }
    }
  }
}

// ---------- combine: out[t] = obuf[row0(t)] + obuf[row1(t)] ----------
__global__ __launch_bounds__(256) void combine_k(const float* __restrict__ obuf,
                                                 const int* __restrict__ rows2,
                                                 float* __restrict__ out) {
  int t = blockIdx.x, c = threadIdx.x;       // c indexes float4 within the row
  int r0 = rows2[t * 2], r1 = rows2[t * 2 + 1];
  float4 a = ((const float4*)obuf)[(size_t)r0 * 256 + c];
  float4 b = ((const float4*)obuf)[(size_t)r1 * 256 + c];
  float4 o;
  o.x = a.x + b.x; o.y = a.y + b.y; o.z = a.z + b.z; o.w = a.w + b.w;
  ((float4*)out)[(size_t)t * 256 + c] = o;
}

extern "C" void kernel_launch(void* const* d_in, const int* in_sizes, int n_in,
                              void* d_out, int out_size, void* d_ws, size_t ws_size,
                              hipStream_t stream) {
  const float* tokens   = (const float*)d_in[0];
  const float* router_w = (const float*)d_in[1];
  const float* router_b = (const float*)d_in[2];
  const float* w1       = (const float*)d_in[3];
  const float* b1       = (const float*)d_in[4];
  const float* w2       = (const float*)d_in[5];
  const float* b2       = (const float*)d_in[6];
  float* out = (float*)d_out;

  char* ws = (char*)d_ws;
  u16*   tokb  = (u16*)(ws + TOKB_OFF);
  u16*   w1t   = (u16*)(ws + W1T_OFF);
  float* obuf  = (float*)(ws + OBUF_OFF);     // reuses w1t region after ffn1
  u16*   w2t   = (u16*)(ws + W2T_OFF);
  u16*   h     = (u16*)(ws + H_OFF);
  int*   rlt   = (int*)(ws + RLT_OFF);
  float* rlg   = (float*)(ws + RLG_OFF);
  int*   cnt   = (int*)(ws + CNT_OFF);
  int*   e01   = (int*)(ws + E01_OFF);
  int*   slots = (int*)(ws + SLOT_OFF);
  float* gates = (float*)(ws + GATE_OFF);
  int*   rows2 = (int*)(ws + ROWS2_OFF);

  hipMemsetAsync(cnt, 0, 32, stream);

  cvt_tokens_k<<<(N_TOKENS * HIDDEN / 4) / 256, 256, 0, stream>>>(tokens, tokb);
  cvt_transpose_k<<<dim3(EXPAND / 32, HIDDEN / 32, N_EXP), dim3(32, 8), 0, stream>>>(
      w1, w1t, HIDDEN, EXPAND);
  cvt_transpose_k<<<dim3(HIDDEN / 32, EXPAND / 32, N_EXP), dim3(32, 8), 0, stream>>>(
      w2, w2t, EXPAND, HIDDEN);
  router_k<<<N_TOKENS / 4, 256, 0, stream>>>(tokens, router_w, router_b,
                                             e01, slots, gates, cnt);
  build_k<<<N_TOKENS / 256, 256, 0, stream>>>(e01, slots, gates, cnt, rlt, rlg, rows2);
  ffn1_k<<<dim3(EXPAND / 128, 32, N_EXP), 256, 0, stream>>>(tokb, w1t, b1, rlt, cnt, h);
  ffn2_k<<<dim3(HIDDEN / 128, 32, N_EXP), 256, 0, stream>>>(h, w2t, b2, rlg, cnt, obuf);
  combine_k<<<N_TOKENS, 256, 0, stream>>>(obuf, rows2, out);
}